// Round 1
// baseline (599.425 us; speedup 1.0000x reference)
//
#include <hip/hip_runtime.h>

#define NWIN 2048
#define NTOK 64
#define CDIM 256
#define NH 8
#define HD 32
#define QSCALE 0.17677669529663689f   // 32^-0.5

// LDS stride (bf16 units): 264 -> row stride 528 B = 132 words; 132 mod 32 = 4
// so 16 rows spread over 8 bank-quads -> 2-way (free, m136) on b128 access.
#define LDA 264

typedef __bf16 bf16x8 __attribute__((ext_vector_type(8)));
typedef float  f32x4  __attribute__((ext_vector_type(4)));
typedef unsigned int u32x4 __attribute__((ext_vector_type(4)));

__device__ __forceinline__ unsigned short f2bf(float f) {
    union { float f; unsigned u; } v; v.f = f;
    unsigned r = v.u + 0x7FFFu + ((v.u >> 16) & 1u);   // RNE
    return (unsigned short)(r >> 16);
}

__device__ __forceinline__ bf16x8 ld16(const unsigned short* p) {
    return *(const bf16x8*)p;
}

__device__ __forceinline__ unsigned cvtpk(float lo, float hi) {
    unsigned r;
    asm("v_cvt_pk_bf16_f32 %0, %1, %2" : "=v"(r) : "v"(lo), "v"(hi));
    return r;
}
__device__ __forceinline__ void pl32(unsigned &a, unsigned &b) {
    // a' = {a.lane[0:31], b.lane[0:31]}, b' = {a.lane[32:63], b.lane[32:63]}
    asm("v_permlane32_swap_b32 %0, %1" : "+v"(a), "+v"(b));
}
__device__ __forceinline__ void pl16(unsigned &a, unsigned &b) {
    // a' = {a.r0, b.r0, a.r2, b.r2}, b' = {a.r1, b.r1, a.r3, b.r3} (16-lane rows)
    asm("v_permlane16_swap_b32 %0, %1" : "+v"(a), "+v"(b));
}

// In-register C-layout -> frag exchange over a 32-long axis.
// Input: two MFMA C-accs t0 (axis 0..15), t1 (axis 16..31); lane(quad,lm) holds
// axis elements 16*t + 4*quad + reg for its lm.
// Output: bf16x8 where lane(quad',lm) holds axis elements 8*quad'..8*quad'+7
// = exactly the A/B-frag k-layout of mfma_f32_16x16x32_bf16 (k = (l>>4)*8+e).
__device__ __forceinline__ bf16x8 xchg32(f32x4 t0, f32x4 t1) {
    unsigned u00 = cvtpk(t0[0], t0[1]);   // axis 4q+0,1 of tile 0
    unsigned u01 = cvtpk(t0[2], t0[3]);   // axis 4q+2,3 of tile 0
    unsigned u10 = cvtpk(t1[0], t1[1]);   // tile 1
    unsigned u11 = cvtpk(t1[2], t1[3]);
    pl32(u00, u10);   // u00={t0.q01,t1.q01}, u10={t0.q23,t1.q23}
    pl32(u01, u11);
    pl16(u00, u10);   // u00=d[0] (k 8q'+0,1), u10=d[2] (k 8q'+4,5)
    pl16(u01, u11);   // u01=d[1],             u11=d[3]
    union { u32x4 u; bf16x8 v; } r;
    r.u = (u32x4){u00, u01, u10, u11};
    return r.v;
}

// ---- precast: weights fp32->bf16; bias_table -> relbQ[h][q][k] fp32 ----
__global__ void precast_kernel(const float* __restrict__ wq, const float* __restrict__ wp,
                               const float* __restrict__ bt,
                               unsigned short* __restrict__ wqb, unsigned short* __restrict__ wpb,
                               float* __restrict__ relbQ) {
    int i = blockIdx.x * 256 + threadIdx.x;
    if (i < 196608) {
        wqb[i] = f2bf(wq[i]);
    } else if (i < 262144) {
        wpb[i - 196608] = f2bf(wp[i - 196608]);
    } else if (i < 294912) {
        int j = i - 262144;            // h*4096 + q*64 + k (q = query row, k = key col)
        int h = j >> 12;
        int q = (j >> 6) & 63;
        int k = j & 63;
        int yq = q >> 3, xq = q & 7, yk = k >> 3, xk = k & 7;
        int idx = (yq - yk + 7) * 15 + (xq - xk + 7);
        relbQ[j] = bt[idx * NH + h];
    }
}

__global__ __launch_bounds__(512, 4)
void win_attn_kernel(const float* __restrict__ x, const float* __restrict__ mask,
                     const float* __restrict__ bq, const float* __restrict__ bp,
                     const unsigned short* __restrict__ wq, const unsigned short* __restrict__ wp,
                     const float* __restrict__ relbQ, float* __restrict__ out) {
    // 67,584 B of LDS -> 2 blocks/CU
    __shared__ __align__(16) unsigned short sm[2 * NTOK * LDA];
    unsigned short* sA = sm;                  // x (bf16), read-only after phase 0
    unsigned short* sO = sm + NTOK * LDA;     // attn_out (bf16)

    const int b    = blockIdx.x;
    const int tid  = threadIdx.x;
    const int wv   = tid >> 6;            // wave id == head id
    const int lane = tid & 63;
    const int lm   = lane & 15;
    const int quad = lane >> 4;
    const f32x4 fzero = {0.f, 0.f, 0.f, 0.f};

    // ---------- Phase 0: stage x window, fp32 -> bf16 (cvt_pk pairs) ----------
    {
        const int row = tid >> 3;             // 64 rows, 8 threads/row
        const int c0  = (tid & 7) * 32;
        const float4* gx = (const float4*)(x + ((size_t)b * NTOK + row) * CDIM + c0);
        unsigned short* dst = sA + row * LDA + c0;
        #pragma unroll
        for (int i = 0; i < 4; ++i) {
            float4 a = gx[2 * i];
            float4 c = gx[2 * i + 1];
            u32x4 w = { cvtpk(a.x, a.y), cvtpk(a.z, a.w), cvtpk(c.x, c.y), cvtpk(c.z, c.w) };
            *(u32x4*)(dst + i * 8) = w;
        }
    }
    __syncthreads();

    const int h = wv;

    // ---------- Phase 1a: [Q;K]^T = W_qk . x^T  (keeps token on lane&15) ----------
    // Output C-layout per (ft,nt): col = token (lm), row = feature 4*quad+reg.
    bf16x8 qf[4];   // Q B-frags: (query = nt*16+lm, d = quad*8..+8)
    bf16x8 kf[4];   // K A-frags: (key   = nt*16+lm, d = quad*8..+8)
    {
        f32x4 qk[4][4];   // [ftile][ttile]
        #pragma unroll
        for (int ft = 0; ft < 4; ++ft)
            #pragma unroll
            for (int nt = 0; nt < 4; ++nt) qk[ft][nt] = fzero;

        const int fb[4] = { h*HD, h*HD + 16, CDIM + h*HD, CDIM + h*HD + 16 };
        #pragma unroll
        for (int ks = 0; ks < 8; ++ks) {
            bf16x8 xa[4], wf[4];
            #pragma unroll
            for (int nt = 0; nt < 4; ++nt)
                xa[nt] = ld16(sA + (nt * 16 + lm) * LDA + ks * 32 + quad * 8);
            #pragma unroll
            for (int ft = 0; ft < 4; ++ft)
                wf[ft] = ld16(wq + (fb[ft] + lm) * CDIM + ks * 32 + quad * 8);
            #pragma unroll
            for (int ft = 0; ft < 4; ++ft)
                #pragma unroll
                for (int nt = 0; nt < 4; ++nt)
                    qk[ft][nt] = __builtin_amdgcn_mfma_f32_16x16x32_bf16(wf[ft], xa[nt], qk[ft][nt], 0, 0, 0);
        }

        const float4 bQ0 = *(const float4*)(bq + h*HD + quad*4);
        const float4 bQ1 = *(const float4*)(bq + h*HD + 16 + quad*4);
        const float4 bK0 = *(const float4*)(bq + CDIM + h*HD + quad*4);
        const float4 bK1 = *(const float4*)(bq + CDIM + h*HD + 16 + quad*4);
        const float q0v[4] = {bQ0.x, bQ0.y, bQ0.z, bQ0.w};
        const float q1v[4] = {bQ1.x, bQ1.y, bQ1.z, bQ1.w};
        const float k0v[4] = {bK0.x, bK0.y, bK0.z, bK0.w};
        const float k1v[4] = {bK1.x, bK1.y, bK1.z, bK1.w};

        #pragma unroll
        for (int nt = 0; nt < 4; ++nt) {
            #pragma unroll
            for (int r = 0; r < 4; ++r) {
                qk[0][nt][r] = (qk[0][nt][r] + q0v[r]) * QSCALE;
                qk[1][nt][r] = (qk[1][nt][r] + q1v[r]) * QSCALE;
                qk[2][nt][r] += k0v[r];
                qk[3][nt][r] += k1v[r];
            }
            qf[nt] = xchg32(qk[0][nt], qk[1][nt]);
            kf[nt] = xchg32(qk[2][nt], qk[3][nt]);
        }
    }

    // ---------- Phase 1b: V = x . Wv^T (normal orientation) ----------
    // Output C-layout per (mt,t): col = d (t*16+lm), row = token 4*quad+reg.
    bf16x8 vf[2][2];  // V^T A-frags: (d = t*16+lm, key = kk*32 + quad*8..+8)
    {
        f32x4 va[4][2];   // [ttile(tokens)][dtile]
        #pragma unroll
        for (int mt = 0; mt < 4; ++mt) { va[mt][0] = fzero; va[mt][1] = fzero; }

        #pragma unroll
        for (int ks = 0; ks < 8; ++ks) {
            bf16x8 xa[4], wfv[2];
            #pragma unroll
            for (int mt = 0; mt < 4; ++mt)
                xa[mt] = ld16(sA + (mt * 16 + lm) * LDA + ks * 32 + quad * 8);
            #pragma unroll
            for (int t = 0; t < 2; ++t)
                wfv[t] = ld16(wq + (2*CDIM + h*HD + t*16 + lm) * CDIM + ks * 32 + quad * 8);
            #pragma unroll
            for (int mt = 0; mt < 4; ++mt)
                #pragma unroll
                for (int t = 0; t < 2; ++t)
                    va[mt][t] = __builtin_amdgcn_mfma_f32_16x16x32_bf16(xa[mt], wfv[t], va[mt][t], 0, 0, 0);
        }

        const float bV0 = bq[2*CDIM + h*HD + lm];
        const float bV1 = bq[2*CDIM + h*HD + 16 + lm];
        #pragma unroll
        for (int mt = 0; mt < 4; ++mt)
            #pragma unroll
            for (int r = 0; r < 4; ++r) { va[mt][0][r] += bV0; va[mt][1][r] += bV1; }

        #pragma unroll
        for (int t = 0; t < 2; ++t)
            #pragma unroll
            for (int kk = 0; kk < 2; ++kk)
                vf[t][kk] = xchg32(va[2*kk][t], va[2*kk + 1][t]);   // exchange over token axis
    }

    // ---------- Phase 2: attention, fully in registers (no barrier since 1a) ----------
    {
        const float* maskb = mask + (size_t)b * (NTOK * NTOK);
        const float* relh  = relbQ + h * (NTOK * NTOK);

        #pragma unroll
        for (int rc = 0; rc < 4; ++rc) {
            // S^T chunk: 64 keys x 16 queries; col = query (lm), row = key 4*quad+reg+16*jt
            f32x4 s[4];
            #pragma unroll
            for (int jt = 0; jt < 4; ++jt)
                s[jt] = __builtin_amdgcn_mfma_f32_16x16x32_bf16(kf[jt], qf[rc], fzero, 0, 0, 0);

            const float* mrow = maskb + (rc * 16 + lm) * 64;
            const float* rrow = relh  + (rc * 16 + lm) * 64;
            #pragma unroll
            for (int jt = 0; jt < 4; ++jt) {
                float4 rb = *(const float4*)(rrow + jt * 16 + quad * 4);
                float4 mk = *(const float4*)(mrow + jt * 16 + quad * 4);
                const float rbv[4] = {rb.x, rb.y, rb.z, rb.w};
                const float mkv[4] = {mk.x, mk.y, mk.z, mk.w};
                #pragma unroll
                for (int r = 0; r < 4; ++r) s[jt][r] += rbv[r] + mkv[r];
            }

            // softmax over keys: 16 in-lane + 2 cross-quad shuffles
            float mx = s[0][0];
            #pragma unroll
            for (int jt = 0; jt < 4; ++jt)
                #pragma unroll
                for (int r = 0; r < 4; ++r) mx = fmaxf(mx, s[jt][r]);
            mx = fmaxf(mx, __shfl_xor(mx, 16, 64));
            mx = fmaxf(mx, __shfl_xor(mx, 32, 64));

            float sum = 0.f;
            #pragma unroll
            for (int jt = 0; jt < 4; ++jt)
                #pragma unroll
                for (int r = 0; r < 4; ++r) {
                    float e = __expf(s[jt][r] - mx);
                    s[jt][r] = e;
                    sum += e;
                }
            sum += __shfl_xor(sum, 16, 64);
            sum += __shfl_xor(sum, 32, 64);
            const float inv = 1.0f / sum;   // defer row scaling to PV output

            // P^T B-frags via exchange over key axis
            bf16x8 pb0 = xchg32(s[0], s[1]);   // keys  0..31
            bf16x8 pb1 = xchg32(s[2], s[3]);   // keys 32..63

            // O^T = V^T . P^T : col = query (lm), row = d 4*quad+reg (+16*dt)
            f32x4 o0 = __builtin_amdgcn_mfma_f32_16x16x32_bf16(vf[0][0], pb0, fzero, 0, 0, 0);
            o0 = __builtin_amdgcn_mfma_f32_16x16x32_bf16(vf[0][1], pb1, o0, 0, 0, 0);
            f32x4 o1 = __builtin_amdgcn_mfma_f32_16x16x32_bf16(vf[1][0], pb0, fzero, 0, 0, 0);
            o1 = __builtin_amdgcn_mfma_f32_16x16x32_bf16(vf[1][1], pb1, o1, 0, 0, 0);
            #pragma unroll
            for (int r = 0; r < 4; ++r) { o0[r] *= inv; o1[r] *= inv; }

            // exchange over d axis -> (token = rc*16+lm, d = quad*8..+8); one b128 write
            bf16x8 ob = xchg32(o0, o1);
            *(bf16x8*)(sO + (rc * 16 + lm) * LDA + h * HD + quad * 8) = ob;
        }
    }
    __syncthreads();   // attn_out complete

    // ---------- Phase 3: out = attn_out @ wp^T + bp; wave wv does cols [wv*32, wv*32+32) ----------
    {
        const int n0 = wv * HD;
        f32x4 acc[4][2];
        #pragma unroll
        for (int mt = 0; mt < 4; ++mt) { acc[mt][0] = fzero; acc[mt][1] = fzero; }

        #pragma unroll
        for (int ks = 0; ks < 8; ++ks) {
            bf16x8 bfr[2];
            #pragma unroll
            for (int nt = 0; nt < 2; ++nt)
                bfr[nt] = ld16(wp + (n0 + nt * 16 + lm) * CDIM + ks * 32 + quad * 8);
            bf16x8 afr[4];
            #pragma unroll
            for (int mt = 0; mt < 4; ++mt)
                afr[mt] = ld16(sO + (mt * 16 + lm) * LDA + ks * 32 + quad * 8);
            #pragma unroll
            for (int mt = 0; mt < 4; ++mt)
                #pragma unroll
                for (int nt = 0; nt < 2; ++nt)
                    acc[mt][nt] = __builtin_amdgcn_mfma_f32_16x16x32_bf16(afr[mt], bfr[nt], acc[mt][nt], 0, 0, 0);
        }

        float bpv[2] = { bp[n0 + lm], bp[n0 + 16 + lm] };
        #pragma unroll
        for (int mt = 0; mt < 4; ++mt)
            #pragma unroll
            for (int nt = 0; nt < 2; ++nt)
                #pragma unroll
                for (int reg = 0; reg < 4; ++reg) {
                    int r = mt * 16 + quad * 4 + reg;
                    out[((size_t)b * NTOK + r) * CDIM + n0 + nt * 16 + lm] = acc[mt][nt][reg] + bpv[nt];
                }
    }
}

extern "C" void kernel_launch(void* const* d_in, const int* in_sizes, int n_in,
                              void* d_out, int out_size, void* d_ws, size_t ws_size,
                              hipStream_t stream) {
    const float* x    = (const float*)d_in[0];
    const float* mask = (const float*)d_in[1];
    const float* wq   = (const float*)d_in[2];
    const float* bq   = (const float*)d_in[3];
    const float* wp   = (const float*)d_in[4];
    const float* bp   = (const float*)d_in[5];
    const float* bt   = (const float*)d_in[6];

    unsigned short* wqb   = (unsigned short*)d_ws;              // 768x256 bf16
    unsigned short* wpb   = wqb + 196608;                        // 256x256 bf16
    float*          relbQ = (float*)((char*)d_ws + 524288);     // 8x64x64 fp32 (h, q, k)
    float*          out   = (float*)d_out;

    precast_kernel<<<1152, 256, 0, stream>>>(wq, wp, bt, wqb, wpb, relbQ);
    win_attn_kernel<<<NWIN, 512, 0, stream>>>(x, mask, bq, bp, wqb, wpb, relbQ, out);
}

// Round 2
// 577.310 us; speedup vs baseline: 1.0383x; 1.0383x over previous
//
#include <hip/hip_runtime.h>

#define NWIN 2048
#define NTOK 64
#define CDIM 256
#define NH 8
#define HD 32
#define QSCALE 0.17677669529663689f   // 32^-0.5

// LDS stride (bf16 units): 264 -> row stride 528 B = 132 words; 132 mod 32 = 4
// so 16 rows spread over 8 bank-quads -> 2-way (free, m136) on b128 access.
#define LDA 264

typedef __bf16 bf16x8 __attribute__((ext_vector_type(8)));
typedef float  f32x4  __attribute__((ext_vector_type(4)));
typedef unsigned int u32x4 __attribute__((ext_vector_type(4)));

__device__ __forceinline__ unsigned short f2bf(float f) {
    union { float f; unsigned u; } v; v.f = f;
    unsigned r = v.u + 0x7FFFu + ((v.u >> 16) & 1u);   // RNE
    return (unsigned short)(r >> 16);
}

__device__ __forceinline__ bf16x8 ld16(const unsigned short* p) {
    return *(const bf16x8*)p;
}

__device__ __forceinline__ unsigned cvtpk(float lo, float hi) {
    unsigned r;
    asm("v_cvt_pk_bf16_f32 %0, %1, %2" : "=v"(r) : "v"(lo), "v"(hi));
    return r;
}
__device__ __forceinline__ void pl32(unsigned &a, unsigned &b) {
    asm("v_permlane32_swap_b32 %0, %1" : "+v"(a), "+v"(b));
}
__device__ __forceinline__ void pl16(unsigned &a, unsigned &b) {
    asm("v_permlane16_swap_b32 %0, %1" : "+v"(a), "+v"(b));
}

// In-register C-layout -> frag exchange over a 32-long axis (verified round 1).
__device__ __forceinline__ bf16x8 xchg32(f32x4 t0, f32x4 t1) {
    unsigned u00 = cvtpk(t0[0], t0[1]);
    unsigned u01 = cvtpk(t0[2], t0[3]);
    unsigned u10 = cvtpk(t1[0], t1[1]);
    unsigned u11 = cvtpk(t1[2], t1[3]);
    pl32(u00, u10);
    pl32(u01, u11);
    pl16(u00, u10);
    pl16(u01, u11);
    union { u32x4 u; bf16x8 v; } r;
    r.u = (u32x4){u00, u01, u10, u11};
    return r.v;
}

// ---- precast: weights fp32->bf16; bias_table -> relbQ[h][q][k] fp32 ----
__global__ void precast_kernel(const float* __restrict__ wq, const float* __restrict__ wp,
                               const float* __restrict__ bt,
                               unsigned short* __restrict__ wqb, unsigned short* __restrict__ wpb,
                               float* __restrict__ relbQ) {
    int i = blockIdx.x * 256 + threadIdx.x;
    if (i < 196608) {
        wqb[i] = f2bf(wq[i]);
    } else if (i < 262144) {
        wpb[i - 196608] = f2bf(wp[i - 196608]);
    } else if (i < 294912) {
        int j = i - 262144;            // h*4096 + q*64 + k
        int h = j >> 12;
        int q = (j >> 6) & 63;
        int k = j & 63;
        int yq = q >> 3, xq = q & 7, yk = k >> 3, xk = k & 7;
        int idx = (yq - yk + 7) * 15 + (xq - xk + 7);
        relbQ[j] = bt[idx * NH + h];
    }
}

// Narrow QK pass: 32 features (2 tiles) x 64 tokens, transposed output.
// Peak live: 8 acc f32x4 (32) + xa[4] (16) + 2 w-frags (8) + persistents.
__device__ __forceinline__ void qk_pass(const unsigned short* sA, const unsigned short* wrow0,
                                        const unsigned short* wrow1, const float* bias0,
                                        float scale, int lm, int quad, bf16x8 outf[4]) {
    const f32x4 fzero = {0.f, 0.f, 0.f, 0.f};
    f32x4 a0[4], a1[4];
    #pragma unroll
    for (int nt = 0; nt < 4; ++nt) { a0[nt] = fzero; a1[nt] = fzero; }

    #pragma unroll
    for (int ks = 0; ks < 8; ++ks) {
        bf16x8 xa[4];
        #pragma unroll
        for (int nt = 0; nt < 4; ++nt)
            xa[nt] = ld16(sA + (nt * 16 + lm) * LDA + ks * 32 + quad * 8);
        bf16x8 wf0 = ld16(wrow0 + ks * 32 + quad * 8);
        bf16x8 wf1 = ld16(wrow1 + ks * 32 + quad * 8);
        #pragma unroll
        for (int nt = 0; nt < 4; ++nt) {
            a0[nt] = __builtin_amdgcn_mfma_f32_16x16x32_bf16(wf0, xa[nt], a0[nt], 0, 0, 0);
            a1[nt] = __builtin_amdgcn_mfma_f32_16x16x32_bf16(wf1, xa[nt], a1[nt], 0, 0, 0);
        }
    }

    const float4 b0 = *(const float4*)(bias0 + quad * 4);
    const float4 b1 = *(const float4*)(bias0 + 16 + quad * 4);
    const float b0v[4] = {b0.x, b0.y, b0.z, b0.w};
    const float b1v[4] = {b1.x, b1.y, b1.z, b1.w};
    #pragma unroll
    for (int nt = 0; nt < 4; ++nt) {
        #pragma unroll
        for (int r = 0; r < 4; ++r) {
            a0[nt][r] = (a0[nt][r] + b0v[r]) * scale;
            a1[nt][r] = (a1[nt][r] + b1v[r]) * scale;
        }
        outf[nt] = xchg32(a0[nt], a1[nt]);
    }
}

__global__ __launch_bounds__(512, 4)
void win_attn_kernel(const float* __restrict__ x, const float* __restrict__ mask,
                     const float* __restrict__ bq, const float* __restrict__ bp,
                     const unsigned short* __restrict__ wq, const unsigned short* __restrict__ wp,
                     const float* __restrict__ relbQ, float* __restrict__ out) {
    // 67,584 B of LDS -> 2 blocks/CU
    __shared__ __align__(16) unsigned short sm[2 * NTOK * LDA];
    unsigned short* sA = sm;                  // x (bf16), read-only after phase 0
    unsigned short* sO = sm + NTOK * LDA;     // attn_out (bf16)

    const int b    = blockIdx.x;
    const int tid  = threadIdx.x;
    const int wv   = tid >> 6;            // wave id == head id
    const int lane = tid & 63;
    const int lm   = lane & 15;
    const int quad = lane >> 4;
    const f32x4 fzero = {0.f, 0.f, 0.f, 0.f};

    // ---------- Phase 0: stage x window, fp32 -> bf16 ----------
    {
        const int row = tid >> 3;             // 64 rows, 8 threads/row
        const int c0  = (tid & 7) * 32;
        const float4* gx = (const float4*)(x + ((size_t)b * NTOK + row) * CDIM + c0);
        unsigned short* dst = sA + row * LDA + c0;
        #pragma unroll
        for (int i = 0; i < 4; ++i) {
            float4 a = gx[2 * i];
            float4 c = gx[2 * i + 1];
            u32x4 w = { cvtpk(a.x, a.y), cvtpk(a.z, a.w), cvtpk(c.x, c.y), cvtpk(c.z, c.w) };
            *(u32x4*)(dst + i * 8) = w;
        }
    }
    __syncthreads();

    const int h = wv;

    // ---------- Phase 1: four narrow passes to keep VGPR+AGPR under the
    // 128/wave budget of __launch_bounds__(512,4). Round-1's single wide
    // pass (16 accs live) spilled ~1.2 GB of scratch per dispatch. ----------
    bf16x8 qf[4];     // Q B-frags: (query = nt*16+lm, d = quad*8..+8)
    bf16x8 kf[4];     // K A-frags
    bf16x8 vf[2][2];  // V^T A-frags: (d = t*16+lm, key = kk*32 + quad*8..+8)

    qk_pass(sA, wq + (h*HD + lm) * CDIM, wq + (h*HD + 16 + lm) * CDIM,
            bq + h*HD, QSCALE, lm, quad, qf);
    qk_pass(sA, wq + (CDIM + h*HD + lm) * CDIM, wq + (CDIM + h*HD + 16 + lm) * CDIM,
            bq + CDIM + h*HD, 1.0f, lm, quad, kf);

    #pragma unroll
    for (int t = 0; t < 2; ++t) {
        f32x4 va[4];
        #pragma unroll
        for (int mt = 0; mt < 4; ++mt) va[mt] = fzero;
        const unsigned short* wvp = wq + (2*CDIM + h*HD + t*16 + lm) * CDIM;
        #pragma unroll
        for (int ks = 0; ks < 8; ++ks) {
            bf16x8 xa[4];
            #pragma unroll
            for (int mt = 0; mt < 4; ++mt)
                xa[mt] = ld16(sA + (mt * 16 + lm) * LDA + ks * 32 + quad * 8);
            bf16x8 wfv = ld16(wvp + ks * 32 + quad * 8);
            #pragma unroll
            for (int mt = 0; mt < 4; ++mt)
                va[mt] = __builtin_amdgcn_mfma_f32_16x16x32_bf16(xa[mt], wfv, va[mt], 0, 0, 0);
        }
        const float bV = bq[2*CDIM + h*HD + t*16 + lm];
        #pragma unroll
        for (int mt = 0; mt < 4; ++mt)
            #pragma unroll
            for (int r = 0; r < 4; ++r) va[mt][r] += bV;
        vf[t][0] = xchg32(va[0], va[1]);   // exchange over token axis: keys 0..31
        vf[t][1] = xchg32(va[2], va[3]);   // keys 32..63
    }

    // ---------- Phase 2: attention, fully in registers ----------
    {
        const float* maskb = mask + (size_t)b * (NTOK * NTOK);
        const float* relh  = relbQ + h * (NTOK * NTOK);

        #pragma unroll
        for (int rc = 0; rc < 4; ++rc) {
            // S^T chunk: col = query (lm), row = key 4*quad+reg+16*jt
            f32x4 s[4];
            #pragma unroll
            for (int jt = 0; jt < 4; ++jt)
                s[jt] = __builtin_amdgcn_mfma_f32_16x16x32_bf16(kf[jt], qf[rc], fzero, 0, 0, 0);

            const float* mrow = maskb + (rc * 16 + lm) * 64;
            const float* rrow = relh  + (rc * 16 + lm) * 64;
            #pragma unroll
            for (int jt = 0; jt < 4; ++jt) {
                float4 rb = *(const float4*)(rrow + jt * 16 + quad * 4);
                float4 mk = *(const float4*)(mrow + jt * 16 + quad * 4);
                const float rbv[4] = {rb.x, rb.y, rb.z, rb.w};
                const float mkv[4] = {mk.x, mk.y, mk.z, mk.w};
                #pragma unroll
                for (int r = 0; r < 4; ++r) s[jt][r] += rbv[r] + mkv[r];
            }

            // softmax over keys: 16 in-lane + 2 cross-quad shuffles
            float mx = s[0][0];
            #pragma unroll
            for (int jt = 0; jt < 4; ++jt)
                #pragma unroll
                for (int r = 0; r < 4; ++r) mx = fmaxf(mx, s[jt][r]);
            mx = fmaxf(mx, __shfl_xor(mx, 16, 64));
            mx = fmaxf(mx, __shfl_xor(mx, 32, 64));

            float sum = 0.f;
            #pragma unroll
            for (int jt = 0; jt < 4; ++jt)
                #pragma unroll
                for (int r = 0; r < 4; ++r) {
                    float e = __expf(s[jt][r] - mx);
                    s[jt][r] = e;
                    sum += e;
                }
            sum += __shfl_xor(sum, 16, 64);
            sum += __shfl_xor(sum, 32, 64);
            const float inv = 1.0f / sum;   // defer row scaling to PV output

            // P^T B-frags via exchange over key axis
            bf16x8 pb0 = xchg32(s[0], s[1]);   // keys  0..31
            bf16x8 pb1 = xchg32(s[2], s[3]);   // keys 32..63

            // O^T = V^T . P^T : col = query (lm), row = d 4*quad+reg (+16*dt)
            f32x4 o0 = __builtin_amdgcn_mfma_f32_16x16x32_bf16(vf[0][0], pb0, fzero, 0, 0, 0);
            o0 = __builtin_amdgcn_mfma_f32_16x16x32_bf16(vf[0][1], pb1, o0, 0, 0, 0);
            f32x4 o1 = __builtin_amdgcn_mfma_f32_16x16x32_bf16(vf[1][0], pb0, fzero, 0, 0, 0);
            o1 = __builtin_amdgcn_mfma_f32_16x16x32_bf16(vf[1][1], pb1, o1, 0, 0, 0);
            #pragma unroll
            for (int r = 0; r < 4; ++r) { o0[r] *= inv; o1[r] *= inv; }

            // exchange over d axis -> (token = rc*16+lm, d = quad*8..+8)
            bf16x8 ob = xchg32(o0, o1);
            *(bf16x8*)(sO + (rc * 16 + lm) * LDA + h * HD + quad * 8) = ob;
        }
    }
    __syncthreads();   // attn_out complete

    // ---------- Phase 3: out = attn_out @ wp^T + bp ----------
    {
        const int n0 = wv * HD;
        f32x4 acc[4][2];
        #pragma unroll
        for (int mt = 0; mt < 4; ++mt) { acc[mt][0] = fzero; acc[mt][1] = fzero; }

        #pragma unroll
        for (int ks = 0; ks < 8; ++ks) {
            bf16x8 bfr[2];
            #pragma unroll
            for (int nt = 0; nt < 2; ++nt)
                bfr[nt] = ld16(wp + (n0 + nt * 16 + lm) * CDIM + ks * 32 + quad * 8);
            bf16x8 afr[4];
            #pragma unroll
            for (int mt = 0; mt < 4; ++mt)
                afr[mt] = ld16(sO + (mt * 16 + lm) * LDA + ks * 32 + quad * 8);
            #pragma unroll
            for (int mt = 0; mt < 4; ++mt)
                #pragma unroll
                for (int nt = 0; nt < 2; ++nt)
                    acc[mt][nt] = __builtin_amdgcn_mfma_f32_16x16x32_bf16(afr[mt], bfr[nt], acc[mt][nt], 0, 0, 0);
        }

        float bpv[2] = { bp[n0 + lm], bp[n0 + 16 + lm] };
        #pragma unroll
        for (int mt = 0; mt < 4; ++mt)
            #pragma unroll
            for (int nt = 0; nt < 2; ++nt)
                #pragma unroll
                for (int reg = 0; reg < 4; ++reg) {
                    int r = mt * 16 + quad * 4 + reg;
                    out[((size_t)b * NTOK + r) * CDIM + n0 + nt * 16 + lm] = acc[mt][nt][reg] + bpv[nt];
                }
    }
}

extern "C" void kernel_launch(void* const* d_in, const int* in_sizes, int n_in,
                              void* d_out, int out_size, void* d_ws, size_t ws_size,
                              hipStream_t stream) {
    const float* x    = (const float*)d_in[0];
    const float* mask = (const float*)d_in[1];
    const float* wq   = (const float*)d_in[2];
    const float* bq   = (const float*)d_in[3];
    const float* wp   = (const float*)d_in[4];
    const float* bp   = (const float*)d_in[5];
    const float* bt   = (const float*)d_in[6];

    unsigned short* wqb   = (unsigned short*)d_ws;              // 768x256 bf16
    unsigned short* wpb   = wqb + 196608;                        // 256x256 bf16
    float*          relbQ = (float*)((char*)d_ws + 524288);     // 8x64x64 fp32 (h, q, k)
    float*          out   = (float*)d_out;

    precast_kernel<<<1152, 256, 0, stream>>>(wq, wp, bt, wqb, wpb, relbQ);
    win_attn_kernel<<<NWIN, 512, 0, stream>>>(x, mask, bq, bp, wqb, wpb, relbQ, out);
}

// Round 3
// 419.693 us; speedup vs baseline: 1.4282x; 1.3756x over previous
//
#include <hip/hip_runtime.h>

#define NWIN 2048
#define NTOK 64
#define CDIM 256
#define NH 8
#define HD 32
#define QSCALE 0.17677669529663689f   // 32^-0.5

// LDS stride for x / attn_out tiles (bf16 units): 264 -> row stride 528 B =
// 132 words; 132 mod 32 = 4 -> 2-way on b128 access (free, m136).
#define LDA 264
// LDS stride for the mask tile (f32 units): 68 -> lane stride 68 words,
// lm*68 mod 32 = lm*4 -> 2-way on the phase-2 float4 reads (free).
#define LDM 68

typedef __bf16 bf16x8 __attribute__((ext_vector_type(8)));
typedef float  f32x4  __attribute__((ext_vector_type(4)));
typedef unsigned int u32x4 __attribute__((ext_vector_type(4)));

__device__ __forceinline__ unsigned short f2bf(float f) {
    union { float f; unsigned u; } v; v.f = f;
    unsigned r = v.u + 0x7FFFu + ((v.u >> 16) & 1u);   // RNE
    return (unsigned short)(r >> 16);
}

__device__ __forceinline__ bf16x8 ld16(const unsigned short* p) {
    return *(const bf16x8*)p;
}

__device__ __forceinline__ unsigned cvtpk(float lo, float hi) {
    unsigned r;
    asm("v_cvt_pk_bf16_f32 %0, %1, %2" : "=v"(r) : "v"(lo), "v"(hi));
    return r;
}
__device__ __forceinline__ void pl32(unsigned &a, unsigned &b) {
    asm("v_permlane32_swap_b32 %0, %1" : "+v"(a), "+v"(b));
}
__device__ __forceinline__ void pl16(unsigned &a, unsigned &b) {
    asm("v_permlane16_swap_b32 %0, %1" : "+v"(a), "+v"(b));
}

// In-register C-layout -> A/B-frag exchange over a 32-long axis (verified r1/r2).
__device__ __forceinline__ bf16x8 xchg32(f32x4 t0, f32x4 t1) {
    unsigned u00 = cvtpk(t0[0], t0[1]);
    unsigned u01 = cvtpk(t0[2], t0[3]);
    unsigned u10 = cvtpk(t1[0], t1[1]);
    unsigned u11 = cvtpk(t1[2], t1[3]);
    pl32(u00, u10);
    pl32(u01, u11);
    pl16(u00, u10);
    pl16(u01, u11);
    union { u32x4 u; bf16x8 v; } r;
    r.u = (u32x4){u00, u01, u10, u11};
    return r.v;
}

// ---- precast: weights fp32->bf16; bias_table -> relbQ[h][q][k] fp32 ----
__global__ void precast_kernel(const float* __restrict__ wq, const float* __restrict__ wp,
                               const float* __restrict__ bt,
                               unsigned short* __restrict__ wqb, unsigned short* __restrict__ wpb,
                               float* __restrict__ relbQ) {
    int i = blockIdx.x * 256 + threadIdx.x;
    if (i < 196608) {
        wqb[i] = f2bf(wq[i]);
    } else if (i < 262144) {
        wpb[i - 196608] = f2bf(wp[i - 196608]);
    } else if (i < 294912) {
        int j = i - 262144;            // h*4096 + q*64 + k
        int h = j >> 12;
        int q = (j >> 6) & 63;
        int k = j & 63;
        int yq = q >> 3, xq = q & 7, yk = k >> 3, xk = k & 7;
        int idx = (yq - yk + 7) * 15 + (xq - xk + 7);
        relbQ[j] = bt[idx * NH + h];
    }
}

// launch_bounds(512,2): 256 unified regs/wave. Round 1/2 proved that the
// 128-reg budget of (512,4) splits 64 arch / 64 acc and spills ~1 GB of
// scratch per dispatch (WRITE_SIZE 878-965 MB vs 131 MB of output).
__global__ __launch_bounds__(512, 2)
void win_attn_kernel(const float* __restrict__ x, const float* __restrict__ mask,
                     const float* __restrict__ bq, const float* __restrict__ bp,
                     const unsigned short* __restrict__ wq, const unsigned short* __restrict__ wp,
                     const float* __restrict__ relbQ, float* __restrict__ out) {
    // 67,584 B bf16 tiles + 17,408 B mask tile = 84,992 B of LDS
    __shared__ __align__(16) unsigned char smraw[2 * NTOK * LDA * 2 + NTOK * LDM * 4];
    unsigned short* sA = (unsigned short*)smraw;             // x (bf16)
    unsigned short* sO = sA + NTOK * LDA;                    // attn_out (bf16)
    float*          sM = (float*)(smraw + 2 * NTOK * LDA * 2); // mask (f32)

    const int b    = blockIdx.x;
    const int tid  = threadIdx.x;
    const int wv   = tid >> 6;            // wave id == head id
    const int lane = tid & 63;
    const int lm   = lane & 15;
    const int quad = lane >> 4;
    const f32x4 fzero = {0.f, 0.f, 0.f, 0.f};

    // ---------- Phase 0: stage x (fp32->bf16) and mask (f32) into LDS ----------
    {
        const int row = tid >> 3;             // 64 rows, 8 threads/row
        const int c0  = (tid & 7) * 32;
        const float4* gx = (const float4*)(x + ((size_t)b * NTOK + row) * CDIM + c0);
        unsigned short* dst = sA + row * LDA + c0;
        #pragma unroll
        for (int i = 0; i < 4; ++i) {
            float4 a = gx[2 * i];
            float4 c = gx[2 * i + 1];
            u32x4 w = { cvtpk(a.x, a.y), cvtpk(a.z, a.w), cvtpk(c.x, c.y), cvtpk(c.z, c.w) };
            *(u32x4*)(dst + i * 8) = w;
        }
        // mask: 64 x 64 f32, 8 f32 per thread (T14: HBM latency of the mask
        // hides under phase 1 instead of stalling phase 2's softmax).
        const int mc0 = (tid & 7) * 8;
        const float4* gm = (const float4*)(mask + (size_t)b * (NTOK * NTOK) + row * 64 + mc0);
        float4 m0 = gm[0], m1 = gm[1];
        *(float4*)(sM + row * LDM + mc0)     = m0;
        *(float4*)(sM + row * LDM + mc0 + 4) = m1;
    }
    __syncthreads();

    const int h = wv;

    // ---------- Phase 1a: [Q;K]^T = W_qk . x^T (wide pass, 16 accs) ----------
    bf16x8 qf[4];     // Q B-frags: (query = nt*16+lm, d = quad*8..+8)
    bf16x8 kf[4];     // K A-frags
    {
        f32x4 qk[4][4];   // [ftile][ttile]
        #pragma unroll
        for (int ft = 0; ft < 4; ++ft)
            #pragma unroll
            for (int nt = 0; nt < 4; ++nt) qk[ft][nt] = fzero;

        const int fb[4] = { h*HD, h*HD + 16, CDIM + h*HD, CDIM + h*HD + 16 };
        #pragma unroll
        for (int ks = 0; ks < 8; ++ks) {
            bf16x8 xa[4], wf[4];
            #pragma unroll
            for (int nt = 0; nt < 4; ++nt)
                xa[nt] = ld16(sA + (nt * 16 + lm) * LDA + ks * 32 + quad * 8);
            #pragma unroll
            for (int ft = 0; ft < 4; ++ft)
                wf[ft] = ld16(wq + (fb[ft] + lm) * CDIM + ks * 32 + quad * 8);
            #pragma unroll
            for (int ft = 0; ft < 4; ++ft)
                #pragma unroll
                for (int nt = 0; nt < 4; ++nt)
                    qk[ft][nt] = __builtin_amdgcn_mfma_f32_16x16x32_bf16(wf[ft], xa[nt], qk[ft][nt], 0, 0, 0);
        }

        const float4 bQ0 = *(const float4*)(bq + h*HD + quad*4);
        const float4 bQ1 = *(const float4*)(bq + h*HD + 16 + quad*4);
        const float4 bK0 = *(const float4*)(bq + CDIM + h*HD + quad*4);
        const float4 bK1 = *(const float4*)(bq + CDIM + h*HD + 16 + quad*4);
        const float q0v[4] = {bQ0.x, bQ0.y, bQ0.z, bQ0.w};
        const float q1v[4] = {bQ1.x, bQ1.y, bQ1.z, bQ1.w};
        const float k0v[4] = {bK0.x, bK0.y, bK0.z, bK0.w};
        const float k1v[4] = {bK1.x, bK1.y, bK1.z, bK1.w};

        #pragma unroll
        for (int nt = 0; nt < 4; ++nt) {
            #pragma unroll
            for (int r = 0; r < 4; ++r) {
                qk[0][nt][r] = (qk[0][nt][r] + q0v[r]) * QSCALE;
                qk[1][nt][r] = (qk[1][nt][r] + q1v[r]) * QSCALE;
                qk[2][nt][r] += k0v[r];
                qk[3][nt][r] += k1v[r];
            }
            qf[nt] = xchg32(qk[0][nt], qk[1][nt]);
            kf[nt] = xchg32(qk[2][nt], qk[3][nt]);
        }
    }

    // ---------- Phase 1b: V = x . Wv^T (normal orientation) ----------
    bf16x8 vf[2][2];  // V^T A-frags: (d = t*16+lm, key = kk*32 + quad*8..+8)
    {
        f32x4 va[4][2];   // [ttile(tokens)][dtile]
        #pragma unroll
        for (int mt = 0; mt < 4; ++mt) { va[mt][0] = fzero; va[mt][1] = fzero; }

        #pragma unroll
        for (int ks = 0; ks < 8; ++ks) {
            bf16x8 xa[4], wfv[2];
            #pragma unroll
            for (int mt = 0; mt < 4; ++mt)
                xa[mt] = ld16(sA + (mt * 16 + lm) * LDA + ks * 32 + quad * 8);
            #pragma unroll
            for (int t = 0; t < 2; ++t)
                wfv[t] = ld16(wq + (2*CDIM + h*HD + t*16 + lm) * CDIM + ks * 32 + quad * 8);
            #pragma unroll
            for (int mt = 0; mt < 4; ++mt)
                #pragma unroll
                for (int t = 0; t < 2; ++t)
                    va[mt][t] = __builtin_amdgcn_mfma_f32_16x16x32_bf16(xa[mt], wfv[t], va[mt][t], 0, 0, 0);
        }

        const float bV0 = bq[2*CDIM + h*HD + lm];
        const float bV1 = bq[2*CDIM + h*HD + 16 + lm];
        #pragma unroll
        for (int mt = 0; mt < 4; ++mt)
            #pragma unroll
            for (int r = 0; r < 4; ++r) { va[mt][0][r] += bV0; va[mt][1][r] += bV1; }

        #pragma unroll
        for (int t = 0; t < 2; ++t) {
            vf[t][0] = xchg32(va[0][t], va[1][t]);   // keys  0..31
            vf[t][1] = xchg32(va[2][t], va[3][t]);   // keys 32..63
        }
    }

    // ---------- Phase 2: attention, fully in registers ----------
    {
        const float* relh = relbQ + h * (NTOK * NTOK);

        #pragma unroll
        for (int rc = 0; rc < 4; ++rc) {
            // S^T chunk: col = query (lm), row = key 4*quad+reg+16*jt
            f32x4 s[4];
            #pragma unroll
            for (int jt = 0; jt < 4; ++jt)
                s[jt] = __builtin_amdgcn_mfma_f32_16x16x32_bf16(kf[jt], qf[rc], fzero, 0, 0, 0);

            const float* mrow = sM   + (rc * 16 + lm) * LDM;
            const float* rrow = relh + (rc * 16 + lm) * 64;
            #pragma unroll
            for (int jt = 0; jt < 4; ++jt) {
                float4 rb = *(const float4*)(rrow + jt * 16 + quad * 4);
                float4 mk = *(const float4*)(mrow + jt * 16 + quad * 4);
                const float rbv[4] = {rb.x, rb.y, rb.z, rb.w};
                const float mkv[4] = {mk.x, mk.y, mk.z, mk.w};
                #pragma unroll
                for (int r = 0; r < 4; ++r) s[jt][r] += rbv[r] + mkv[r];
            }

            // softmax over keys: 16 in-lane + 2 cross-quad shuffles
            float mx = s[0][0];
            #pragma unroll
            for (int jt = 0; jt < 4; ++jt)
                #pragma unroll
                for (int r = 0; r < 4; ++r) mx = fmaxf(mx, s[jt][r]);
            mx = fmaxf(mx, __shfl_xor(mx, 16, 64));
            mx = fmaxf(mx, __shfl_xor(mx, 32, 64));

            float sum = 0.f;
            #pragma unroll
            for (int jt = 0; jt < 4; ++jt)
                #pragma unroll
                for (int r = 0; r < 4; ++r) {
                    float e = __expf(s[jt][r] - mx);
                    s[jt][r] = e;
                    sum += e;
                }
            sum += __shfl_xor(sum, 16, 64);
            sum += __shfl_xor(sum, 32, 64);
            const float inv = 1.0f / sum;   // defer row scaling to PV output

            // P^T B-frags via exchange over key axis
            bf16x8 pb0 = xchg32(s[0], s[1]);   // keys  0..31
            bf16x8 pb1 = xchg32(s[2], s[3]);   // keys 32..63

            // O^T = V^T . P^T : col = query (lm), row = d 4*quad+reg (+16*dt)
            f32x4 o0 = __builtin_amdgcn_mfma_f32_16x16x32_bf16(vf[0][0], pb0, fzero, 0, 0, 0);
            o0 = __builtin_amdgcn_mfma_f32_16x16x32_bf16(vf[0][1], pb1, o0, 0, 0, 0);
            f32x4 o1 = __builtin_amdgcn_mfma_f32_16x16x32_bf16(vf[1][0], pb0, fzero, 0, 0, 0);
            o1 = __builtin_amdgcn_mfma_f32_16x16x32_bf16(vf[1][1], pb1, o1, 0, 0, 0);
            #pragma unroll
            for (int r = 0; r < 4; ++r) { o0[r] *= inv; o1[r] *= inv; }

            // exchange over d axis -> (token = rc*16+lm, d = quad*8..+8)
            bf16x8 ob = xchg32(o0, o1);
            *(bf16x8*)(sO + (rc * 16 + lm) * LDA + h * HD + quad * 8) = ob;
        }
    }
    __syncthreads();   // attn_out complete

    // ---------- Phase 3: out = attn_out @ wp^T + bp ----------
    {
        const int n0 = wv * HD;
        f32x4 acc[4][2];
        #pragma unroll
        for (int mt = 0; mt < 4; ++mt) { acc[mt][0] = fzero; acc[mt][1] = fzero; }

        #pragma unroll
        for (int ks = 0; ks < 8; ++ks) {
            bf16x8 bfr[2];
            #pragma unroll
            for (int nt = 0; nt < 2; ++nt)
                bfr[nt] = ld16(wp + (n0 + nt * 16 + lm) * CDIM + ks * 32 + quad * 8);
            bf16x8 afr[4];
            #pragma unroll
            for (int mt = 0; mt < 4; ++mt)
                afr[mt] = ld16(sO + (mt * 16 + lm) * LDA + ks * 32 + quad * 8);
            #pragma unroll
            for (int mt = 0; mt < 4; ++mt)
                #pragma unroll
                for (int nt = 0; nt < 2; ++nt)
                    acc[mt][nt] = __builtin_amdgcn_mfma_f32_16x16x32_bf16(afr[mt], bfr[nt], acc[mt][nt], 0, 0, 0);
        }

        float bpv[2] = { bp[n0 + lm], bp[n0 + 16 + lm] };
        #pragma unroll
        for (int mt = 0; mt < 4; ++mt)
            #pragma unroll
            for (int nt = 0; nt < 2; ++nt)
                #pragma unroll
                for (int reg = 0; reg < 4; ++reg) {
                    int r = mt * 16 + quad * 4 + reg;
                    out[((size_t)b * NTOK + r) * CDIM + n0 + nt * 16 + lm] = acc[mt][nt][reg] + bpv[nt];
                }
    }
}

extern "C" void kernel_launch(void* const* d_in, const int* in_sizes, int n_in,
                              void* d_out, int out_size, void* d_ws, size_t ws_size,
                              hipStream_t stream) {
    const float* x    = (const float*)d_in[0];
    const float* mask = (const float*)d_in[1];
    const float* wq   = (const float*)d_in[2];
    const float* bq   = (const float*)d_in[3];
    const float* wp   = (const float*)d_in[4];
    const float* bp   = (const float*)d_in[5];
    const float* bt   = (const float*)d_in[6];

    unsigned short* wqb   = (unsigned short*)d_ws;              // 768x256 bf16
    unsigned short* wpb   = wqb + 196608;                        // 256x256 bf16
    float*          relbQ = (float*)((char*)d_ws + 524288);     // 8x64x64 fp32 (h, q, k)
    float*          out   = (float*)d_out;

    precast_kernel<<<1152, 256, 0, stream>>>(wq, wp, bt, wqb, wpb, relbQ);
    win_attn_kernel<<<NWIN, 512, 0, stream>>>(x, mask, bq, bp, wqb, wpb, relbQ, out);
}